// Round 4
// baseline (482.188 us; speedup 1.0000x reference)
//
#include <hip/hip_runtime.h>
#include <hip/hip_bf16.h>

// PointTransformerConv block, barrier-free wave-autonomous MFMA edition.
//   CSR counting-sort by dst; scatter materializes sorted srcS/dstS/pd4
//   (pos[d]-pos[s]) so the edge kernel has no index-chasing chain.
//   Edge kernel: each WAVE independently processes 16-edge groups of the
//   dst-sorted edge list. All LDS state is wave-private (sAct rows, segment
//   accumulators) -> ZERO __syncthreads in the main loop. Same-wave LDS
//   RAW ordered via s_waitcnt lgkmcnt(0) + sched_barrier(0) (DS ops are
//   in-order per wave). Gathers issued early, consumed late (T14).
//   All 64x64 GEMMs on mfma_f32_16x16x32_bf16, XOR-swizzled bf16 LDS.

typedef __bf16 bf16x8 __attribute__((ext_vector_type(8)));
typedef short  s16x8  __attribute__((ext_vector_type(8)));
typedef float  f32x4  __attribute__((ext_vector_type(4)));

#define SWZ(b) ((b) ^ ((((b) >> 7) & 7) << 4))

__device__ __forceinline__ unsigned short f2b(float f) {
  union { __hip_bfloat16 h; unsigned short u; } c;
  c.h = __float2bfloat16(f);
  return c.u;
}
__device__ __forceinline__ unsigned int pack2(float a, float b) {
  return (unsigned int)f2b(a) | ((unsigned int)f2b(b) << 16);
}
__device__ __forceinline__ void lds_fence() {
  asm volatile("s_waitcnt lgkmcnt(0)" ::: "memory");
  __builtin_amdgcn_sched_barrier(0);
}

// stage W[k][c] (64x64 fp32 row-major, global) -> dst = W^T [c][k] bf16, swizzled
__device__ __forceinline__ void stage_wt(const float* __restrict__ W, char* dst, int tid) {
  for (int idx = tid; idx < 2048; idx += 256) {
    int c  = idx >> 5;
    int k2 = (idx & 31) << 1;
    float v0 = W[k2 * 64 + c];
    float v1 = W[(k2 + 1) * 64 + c];
    int byte = c * 128 + k2 * 2;
    *(unsigned int*)(dst + SWZ(byte)) = pack2(v0, v1);
  }
}

// wave-local 16-row GEMM: rows 0..15 of actb (2KB wave-private region) x 64 cols, K=64
__device__ __forceinline__ void gemm16(const char* actb, const char* wb,
                                       int g, int m, f32x4 acc[4]) {
  #pragma unroll
  for (int kk = 0; kk < 2; kk++) {
    s16x8 af = *(const s16x8*)(actb + SWZ(m * 128 + g * 16 + kk * 64));
    #pragma unroll
    for (int t = 0; t < 4; t++) {
      s16x8 bf = *(const s16x8*)(wb + SWZ((t * 16 + m) * 128 + g * 16 + kk * 64));
      acc[t] = __builtin_amdgcn_mfma_f32_16x16x32_bf16(
          __builtin_bit_cast(bf16x8, af), __builtin_bit_cast(bf16x8, bf), acc[t], 0, 0, 0);
    }
  }
}

// ---------------- node linears (MFMA) ----------------
__global__ __launch_bounds__(256, 3) void node_mfma_kernel(
    const float* __restrict__ x,
    const float* __restrict__ W_in, const float* __restrict__ b_in,
    const float* __restrict__ W_lin, const float* __restrict__ W_src, const float* __restrict__ W_dst,
    float* __restrict__ a_src, float* __restrict__ a_dst, float* __restrict__ vv,
    int N)
{
  __shared__ __align__(16) char sWinT[8192], sWsT[8192], sWdT[8192], sWlT[8192], sX[8192];
  __shared__ float sB[64];
  int tid = threadIdx.x;
  stage_wt(W_in,  sWinT, tid);
  stage_wt(W_src, sWsT,  tid);
  stage_wt(W_dst, sWdT,  tid);
  stage_wt(W_lin, sWlT,  tid);
  if (tid < 64) sB[tid] = b_in[tid];

  const int lane = tid & 63, wv = tid >> 6;
  const int g = lane >> 4, m = lane & 15;
  const int ew = wv << 4;
  const int srow = tid >> 2, sc0 = (tid & 3) << 4;
  const int ntile = (N + 63) >> 6;

  for (int tile = blockIdx.x; tile < ntile; tile += gridDim.x) {
    const int rbase = tile << 6;
    __syncthreads();
    {
      int gr = rbase + srow; if (gr >= N) gr = N - 1;
      const float4* src = (const float4*)&x[(size_t)gr * 64 + sc0];
      #pragma unroll
      for (int q = 0; q < 4; q++) {
        float4 f = src[q];
        int byte = srow * 128 + sc0 * 2 + q * 8;
        *(unsigned int*)(sX + SWZ(byte))     = pack2(f.x, f.y);
        *(unsigned int*)(sX + SWZ(byte + 4)) = pack2(f.z, f.w);
      }
    }
    __syncthreads();

    f32x4 a0[4] = {};
    gemm16(sX + ew * 128, sWinT, g, m, a0);
    float x1[4][4];
    #pragma unroll
    for (int t = 0; t < 4; t++)
      #pragma unroll
      for (int r = 0; r < 4; r++) x1[t][r] = fmaxf(a0[t][r] + sB[t * 16 + m], 0.f);
    __syncthreads();
    #pragma unroll
    for (int t = 0; t < 4; t++)
      #pragma unroll
      for (int r = 0; r < 4; r++)
        *(unsigned short*)(sX + SWZ((ew + 4 * g + r) * 128 + (t * 16 + m) * 2)) = f2b(x1[t][r]);
    __syncthreads();

    f32x4 as[4] = {}, ad[4] = {}, al[4] = {};
    gemm16(sX + ew * 128, sWsT, g, m, as);
    gemm16(sX + ew * 128, sWdT, g, m, ad);
    gemm16(sX + ew * 128, sWlT, g, m, al);
    #pragma unroll
    for (int t = 0; t < 4; t++)
      #pragma unroll
      for (int r = 0; r < 4; r++) {
        int gr = rbase + ew + 4 * g + r;
        if (gr < N) {
          size_t o = (size_t)gr * 64 + t * 16 + m;
          a_src[o] = as[t][r]; a_dst[o] = ad[t][r]; vv[o] = al[t][r];
        }
      }
  }
}

// ---------------- CSR build ----------------
__global__ void hist_kernel(const int* __restrict__ ei, int* __restrict__ deg, int E, int Etot) {
  int stride = gridDim.x * blockDim.x;
  for (int e = blockIdx.x * blockDim.x + threadIdx.x; e < Etot; e += stride) {
    int d = (e < E) ? ei[E + e] : (e - E);
    atomicAdd(&deg[d], 1);
  }
}

__global__ __launch_bounds__(256) void scanA_kernel(const int* __restrict__ deg, int* __restrict__ chunkSum, int N) {
  __shared__ int s[256];
  int i = blockIdx.x * 256 + threadIdx.x;
  s[threadIdx.x] = (i < N) ? deg[i] : 0;
  __syncthreads();
  for (int off = 128; off > 0; off >>= 1) {
    if (threadIdx.x < off) s[threadIdx.x] += s[threadIdx.x + off];
    __syncthreads();
  }
  if (threadIdx.x == 0) chunkSum[blockIdx.x] = s[0];
}

__global__ __launch_bounds__(256) void scanB_kernel(const int* __restrict__ chunkSum, int* __restrict__ chunkPre, int nchunk) {
  __shared__ int s[256];
  int t = threadIdx.x;
  int v = (t < nchunk) ? chunkSum[t] : 0;
  s[t] = v; __syncthreads();
  for (int off = 1; off < 256; off <<= 1) {
    int x = (t >= off) ? s[t - off] : 0;
    __syncthreads();
    s[t] += x;
    __syncthreads();
  }
  if (t < nchunk) chunkPre[t] = s[t] - v;
}

__global__ __launch_bounds__(256) void scanC_kernel(const int* __restrict__ deg, const int* __restrict__ chunkPre,
                                                    int* __restrict__ cursor, int N) {
  __shared__ int s[256];
  int t = threadIdx.x;
  int i = blockIdx.x * 256 + t;
  int v = (i < N) ? deg[i] : 0;
  s[t] = v; __syncthreads();
  for (int off = 1; off < 256; off <<= 1) {
    int x = (t >= off) ? s[t - off] : 0;
    __syncthreads();
    s[t] += x;
    __syncthreads();
  }
  if (i < N) cursor[i] = chunkPre[blockIdx.x] + s[t] - v;
}

__global__ void scatter_kernel(const int* __restrict__ ei, int* __restrict__ cursor,
                               const float* __restrict__ pos,
                               int* __restrict__ srcS, int* __restrict__ dstS,
                               float4* __restrict__ pd4,
                               int E, int Etot) {
  int stride = gridDim.x * blockDim.x;
  for (int e = blockIdx.x * blockDim.x + threadIdx.x; e < Etot; e += stride) {
    int s, d;
    if (e < E) { s = ei[e]; d = ei[E + e]; }
    else       { s = e - E; d = s; }
    int p = atomicAdd(&cursor[d], 1);
    srcS[p] = s; dstS[p] = d;
    float4 q;
    q.x = pos[d * 3 + 0] - pos[s * 3 + 0];
    q.y = pos[d * 3 + 1] - pos[s * 3 + 1];
    q.z = pos[d * 3 + 2] - pos[s * 3 + 2];
    q.w = 0.f;
    pd4[p] = q;
  }
}

// ---------------- barrier-free fused edge kernel ----------------
__global__ __launch_bounds__(256, 3) void edge_kernel(
    const int* __restrict__ srcS, const int* __restrict__ dstS, const float4* __restrict__ pd4,
    const float* __restrict__ a_src_g, const float* __restrict__ a_dst_g, const float* __restrict__ v_g,
    const float* __restrict__ pos_W1, const float* __restrict__ pos_b1,
    const float* __restrict__ pos_gg, const float* __restrict__ pos_beta,
    const float* __restrict__ pos_W2, const float* __restrict__ pos_b2,
    const float* __restrict__ att_W1, const float* __restrict__ att_b1,
    const float* __restrict__ att_gg, const float* __restrict__ att_beta,
    const float* __restrict__ att_W2, const float* __restrict__ att_b2,
    float* __restrict__ numer, float* __restrict__ denom,
    int G, int gpw)
{
  __shared__ __align__(16) char sW2t[8192], sA1t[8192], sA2t[8192];
  __shared__ __align__(16) char sAct[4][2048];          // wave-private 16 rows x 128B
  __shared__ float sAcc[4][4][128];                     // wave, slot, {N[64],D[64]}
  __shared__ float sPW1[192];
  __shared__ float sPB1[64], sPG[64], sPBeta[64], sPB2[64];
  __shared__ float sAB1[64], sAG[64], sABeta[64], sAB2[64];

  int tid = threadIdx.x;
  stage_wt(pos_W2, sW2t, tid);
  stage_wt(att_W1, sA1t, tid);
  stage_wt(att_W2, sA2t, tid);
  for (int i = tid; i < 192; i += 256) sPW1[i] = pos_W1[i];
  if (tid < 64) {
    sPB1[tid] = pos_b1[tid]; sPG[tid] = pos_gg[tid]; sPBeta[tid] = pos_beta[tid]; sPB2[tid] = pos_b2[tid];
    sAB1[tid] = att_b1[tid]; sAG[tid] = att_gg[tid]; sABeta[tid] = att_beta[tid]; sAB2[tid] = att_b2[tid];
  }
  for (int i = tid; i < 4 * 4 * 128; i += 256) ((float*)sAcc)[i] = 0.f;
  __syncthreads();  // the ONLY block-wide barrier

  const int lane = tid & 63, wv = tid >> 6;
  const int g = lane >> 4, m = lane & 15;
  char* myAct = sAct[wv];
  float (*myAcc)[128] = sAcc[wv];

  const int w  = blockIdx.x * 4 + wv;
  const int g0 = w * gpw;
  int g1 = g0 + gpw; if (g1 > G) g1 = G;

  for (int grp = g0; grp < g1; ++grp) {
    const int ebase = grp << 4;

    // ---- meta (issue immediately; pd independent, dst/src broadcast) ----
    float4 pdr[4];
    #pragma unroll
    for (int r = 0; r < 4; r++) pdr[r] = pd4[ebase + 4 * g + r];
    int dall[16];
    #pragma unroll
    for (int i = 0; i < 16; i++) dall[i] = dstS[ebase + i];
    int mys[4];
    #pragma unroll
    for (int r = 0; r < 4; r++) mys[r] = srcS[ebase + 4 * g + r];

    // ---- segment structure (branchless, static indices) ----
    int myd[4] = {-1, -1, -1, -1};
    int sid_my[4] = {0, 0, 0, 0};
    int fd0 = dall[0], fd1 = -1, fd2 = -1, fd3 = -1;
    int cur = 0;
    #pragma unroll
    for (int i = 0; i < 16; i++) {
      if (i > 0) {
        bool b = (dall[i] != dall[i - 1]);
        cur += b ? 1 : 0;
        fd1 = (b && cur == 1) ? dall[i] : fd1;
        fd2 = (b && cur == 2) ? dall[i] : fd2;
        fd3 = (b && cur == 3) ? dall[i] : fd3;
      }
      bool mine = ((i >> 2) == g);
      const int rr = i & 3;
      if (rr == 0) { myd[0] = mine ? dall[i] : myd[0]; sid_my[0] = mine ? cur : sid_my[0]; }
      if (rr == 1) { myd[1] = mine ? dall[i] : myd[1]; sid_my[1] = mine ? cur : sid_my[1]; }
      if (rr == 2) { myd[2] = mine ? dall[i] : myd[2]; sid_my[2] = mine ? cur : sid_my[2]; }
      if (rr == 3) { myd[3] = mine ? dall[i] : myd[3]; sid_my[3] = mine ? cur : sid_my[3]; }
    }
    const int ns = cur + 1;

    // ---- prefetch a_dst/a_src gathers (consumed after GEMM1) ----
    float adst[16], asrc[16];
    #pragma unroll
    for (int r = 0; r < 4; r++) {
      int dm = myd[r] < 0 ? 0 : myd[r];
      int sm = mys[r];
      #pragma unroll
      for (int t = 0; t < 4; t++) {
        adst[r * 4 + t] = a_dst_g[(size_t)dm * 64 + t * 16 + m];
        asrc[r * 4 + t] = a_src_g[(size_t)sm * 64 + t * 16 + m];
      }
    }

    // ---- Phase A: h = relu(LN(pd @ posW1 + b1)) -> myAct ----
    {
      float h[4][4];  // [t][r]
      #pragma unroll
      for (int r = 0; r < 4; r++) {
        float p0 = pdr[r].x, p1 = pdr[r].y, p2 = pdr[r].z;
        #pragma unroll
        for (int t = 0; t < 4; t++) {
          int c = t * 16 + m;
          h[t][r] = fmaf(p0, sPW1[c], fmaf(p1, sPW1[64 + c], fmaf(p2, sPW1[128 + c], sPB1[c])));
        }
      }
      #pragma unroll
      for (int r = 0; r < 4; r++) {
        float s = h[0][r] + h[1][r] + h[2][r] + h[3][r];
        s += __shfl_xor(s, 1); s += __shfl_xor(s, 2); s += __shfl_xor(s, 4); s += __shfl_xor(s, 8);
        float mean = s * (1.f / 64.f);
        float q = 0.f;
        #pragma unroll
        for (int t = 0; t < 4; t++) { float dd = h[t][r] - mean; q = fmaf(dd, dd, q); }
        q += __shfl_xor(q, 1); q += __shfl_xor(q, 2); q += __shfl_xor(q, 4); q += __shfl_xor(q, 8);
        float rs = rsqrtf(q * (1.f / 64.f) + 1e-5f);
        #pragma unroll
        for (int t = 0; t < 4; t++) {
          int c = t * 16 + m;
          float val = fmaxf(fmaf((h[t][r] - mean) * rs, sPG[c], sPBeta[c]), 0.f);
          *(unsigned short*)(myAct + SWZ((4 * g + r) * 128 + c * 2)) = f2b(val);
        }
      }
    }
    lds_fence();

    // ---- GEMM1: delta = H @ posW2 + b2 ----
    f32x4 dacc[4] = {};
    gemm16(myAct, sW2t, g, m, dacc);
    float del[4][4];
    #pragma unroll
    for (int t = 0; t < 4; t++)
      #pragma unroll
      for (int r = 0; r < 4; r++) del[t][r] = dacc[t][r] + sPB2[t * 16 + m];
    lds_fence();

    // ---- issue v gather (consumed in Phase E) ----
    float vv[16];
    #pragma unroll
    for (int r = 0; r < 4; r++)
      #pragma unroll
      for (int t = 0; t < 4; t++)
        vv[r * 4 + t] = v_g[(size_t)mys[r] * 64 + t * 16 + m];

    // ---- attin = a_dst[d] - a_src[s] + delta -> myAct ----
    #pragma unroll
    for (int r = 0; r < 4; r++)
      #pragma unroll
      for (int t = 0; t < 4; t++) {
        float a = adst[r * 4 + t] - asrc[r * 4 + t] + del[t][r];
        *(unsigned short*)(myAct + SWZ((4 * g + r) * 128 + (t * 16 + m) * 2)) = f2b(a);
      }
    lds_fence();

    // ---- GEMM2 + LN: h2 = relu(LN(attin @ attW1 + b1)) ----
    f32x4 acc2[4] = {};
    gemm16(myAct, sA1t, g, m, acc2);
    float h2[4][4];
    #pragma unroll
    for (int t = 0; t < 4; t++)
      #pragma unroll
      for (int r = 0; r < 4; r++) h2[t][r] = acc2[t][r] + sAB1[t * 16 + m];
    #pragma unroll
    for (int r = 0; r < 4; r++) {
      float s = h2[0][r] + h2[1][r] + h2[2][r] + h2[3][r];
      s += __shfl_xor(s, 1); s += __shfl_xor(s, 2); s += __shfl_xor(s, 4); s += __shfl_xor(s, 8);
      float mean = s * (1.f / 64.f);
      float q = 0.f;
      #pragma unroll
      for (int t = 0; t < 4; t++) { float dd = h2[t][r] - mean; q = fmaf(dd, dd, q); }
      q += __shfl_xor(q, 1); q += __shfl_xor(q, 2); q += __shfl_xor(q, 4); q += __shfl_xor(q, 8);
      float rs = rsqrtf(q * (1.f / 64.f) + 1e-5f);
      #pragma unroll
      for (int t = 0; t < 4; t++) {
        int c = t * 16 + m;
        h2[t][r] = fmaxf(fmaf((h2[t][r] - mean) * rs, sAG[c], sABeta[c]), 0.f);
      }
    }
    lds_fence();
    #pragma unroll
    for (int t = 0; t < 4; t++)
      #pragma unroll
      for (int r = 0; r < 4; r++)
        *(unsigned short*)(myAct + SWZ((4 * g + r) * 128 + (t * 16 + m) * 2)) = f2b(h2[t][r]);
    lds_fence();

    // ---- GEMM3: alpha = h2 @ attW2 ----
    f32x4 acc3[4] = {};
    gemm16(myAct, sA2t, g, m, acc3);

    // ---- Phase E: exp + run-reduce along my 4 rows + slot/direct merge ----
    {
      float aN[4] = {0.f, 0.f, 0.f, 0.f}, aD[4] = {0.f, 0.f, 0.f, 0.f};
      int curS = -1, curD = 0;
      #pragma unroll
      for (int r = 0; r < 4; r++) {
        int d = myd[r];
        if (d < 0) continue;
        int sgid = sid_my[r];
        if (sgid != curS) {
          if (curS >= 0) {
            if (curS < 4) {
              #pragma unroll
              for (int t = 0; t < 4; t++) {
                atomicAdd(&myAcc[curS][t * 16 + m], aN[t]);
                atomicAdd(&myAcc[curS][64 + t * 16 + m], aD[t]);
              }
            } else {
              #pragma unroll
              for (int t = 0; t < 4; t++) {
                atomicAdd(&numer[(size_t)curD * 64 + t * 16 + m], aN[t]);
                atomicAdd(&denom[(size_t)curD * 64 + t * 16 + m], aD[t]);
              }
            }
          }
          curS = sgid; curD = d;
          #pragma unroll
          for (int t = 0; t < 4; t++) { aN[t] = 0.f; aD[t] = 0.f; }
        }
        #pragma unroll
        for (int t = 0; t < 4; t++) {
          float ee = __expf(acc3[t][r] + sAB2[t * 16 + m]);
          aN[t] = fmaf(ee, vv[r * 4 + t] + del[t][r], aN[t]);
          aD[t] += ee;
        }
      }
      if (curS >= 0) {
        if (curS < 4) {
          #pragma unroll
          for (int t = 0; t < 4; t++) {
            atomicAdd(&myAcc[curS][t * 16 + m], aN[t]);
            atomicAdd(&myAcc[curS][64 + t * 16 + m], aD[t]);
          }
        } else {
          #pragma unroll
          for (int t = 0; t < 4; t++) {
            atomicAdd(&numer[(size_t)curD * 64 + t * 16 + m], aN[t]);
            atomicAdd(&denom[(size_t)curD * 64 + t * 16 + m], aD[t]);
          }
        }
      }
    }
    lds_fence();

    // ---- flush wave slots to global, re-zero ----
    {
      const int nsc = ns < 4 ? ns : 4;
      const int fdk[1] = {0}; (void)fdk;
      #pragma unroll
      for (int k = 0; k < 4; k++) {
        int dd = (k == 0) ? fd0 : (k == 1) ? fd1 : (k == 2) ? fd2 : fd3;
        if (k < nsc && dd >= 0) {
          float nv = myAcc[k][lane];
          float dv = myAcc[k][64 + lane];
          atomicAdd(&numer[(size_t)dd * 64 + lane], nv);
          atomicAdd(&denom[(size_t)dd * 64 + lane], dv);
          myAcc[k][lane] = 0.f;
          myAcc[k][64 + lane] = 0.f;
        }
      }
    }
    lds_fence();
  }
}

// ---------------- output linear (MFMA) ----------------
__global__ __launch_bounds__(256) void out_mfma_kernel(
    const float* __restrict__ numer, const float* __restrict__ denom,
    const float* __restrict__ W_out, const float* __restrict__ b_out,
    float* __restrict__ out, int N)
{
  __shared__ __align__(16) char sWoT[8192], sX[8192];
  __shared__ float sB[64];
  int tid = threadIdx.x;
  stage_wt(W_out, sWoT, tid);
  if (tid < 64) sB[tid] = b_out[tid];

  const int lane = tid & 63, wv = tid >> 6;
  const int g = lane >> 4, m = lane & 15;
  const int ew = wv << 4;
  const int srow = tid >> 2, sc0 = (tid & 3) << 4;
  const int ntile = (N + 63) >> 6;

  for (int tile = blockIdx.x; tile < ntile; tile += gridDim.x) {
    const int rbase = tile << 6;
    __syncthreads();
    {
      int gr = rbase + srow; if (gr >= N) gr = N - 1;
      const float4* nsrc = (const float4*)&numer[(size_t)gr * 64 + sc0];
      const float4* dsrc = (const float4*)&denom[(size_t)gr * 64 + sc0];
      #pragma unroll
      for (int q = 0; q < 4; q++) {
        float4 fn = nsrc[q], fd = dsrc[q];
        float m0 = fn.x / fmaxf(fd.x, 1e-16f);
        float m1 = fn.y / fmaxf(fd.y, 1e-16f);
        float m2 = fn.z / fmaxf(fd.z, 1e-16f);
        float m3 = fn.w / fmaxf(fd.w, 1e-16f);
        int byte = srow * 128 + sc0 * 2 + q * 8;
        *(unsigned int*)(sX + SWZ(byte))     = pack2(m0, m1);
        *(unsigned int*)(sX + SWZ(byte + 4)) = pack2(m2, m3);
      }
    }
    __syncthreads();
    f32x4 acc[4] = {};
    gemm16(sX + ew * 128, sWoT, g, m, acc);
    #pragma unroll
    for (int t = 0; t < 4; t++)
      #pragma unroll
      for (int r = 0; r < 4; r++) {
        int gr = rbase + ew + 4 * g + r;
        if (gr < N) out[(size_t)gr * 64 + t * 16 + m] = fmaxf(acc[t][r] + sB[t * 16 + m], 0.f);
      }
  }
}

extern "C" void kernel_launch(void* const* d_in, const int* in_sizes, int n_in,
                              void* d_out, int out_size, void* d_ws, size_t ws_size,
                              hipStream_t stream) {
  (void)n_in; (void)out_size; (void)ws_size;
  const float* x        = (const float*)d_in[0];
  const float* pos      = (const float*)d_in[1];
  const int*   ei       = (const int*)  d_in[2];
  const float* W_in     = (const float*)d_in[3];
  const float* b_in     = (const float*)d_in[4];
  const float* W_lin    = (const float*)d_in[5];
  const float* W_src    = (const float*)d_in[6];
  const float* W_dst    = (const float*)d_in[7];
  const float* pos_W1   = (const float*)d_in[8];
  const float* pos_b1   = (const float*)d_in[9];
  const float* pos_g    = (const float*)d_in[10];
  const float* pos_beta = (const float*)d_in[11];
  const float* pos_W2   = (const float*)d_in[12];
  const float* pos_b2   = (const float*)d_in[13];
  const float* att_W1   = (const float*)d_in[14];
  const float* att_b1   = (const float*)d_in[15];
  const float* att_g    = (const float*)d_in[16];
  const float* att_beta = (const float*)d_in[17];
  const float* att_W2   = (const float*)d_in[18];
  const float* att_b2   = (const float*)d_in[19];
  const float* W_out    = (const float*)d_in[20];
  const float* b_out    = (const float*)d_in[21];

  const int N    = in_sizes[0] / 64;
  const int E    = in_sizes[2] / 2;
  const int Etot = E + N;
  const int Epad = (Etot + 15) & ~15;
  const size_t N64 = (size_t)N * 64;

  float* a_src = (float*)d_ws;
  float* a_dst = a_src + N64;
  float* v     = a_dst + N64;
  float* numer = v + N64;
  float* denom = numer + N64;
  int* deg      = (int*)(denom + N64);
  int* cursor   = deg + N;
  int* chunkSum = cursor + N;
  int* chunkPre = chunkSum + 256;
  int* srcS     = chunkPre + 256;
  int* dstS     = srcS + Epad;
  float4* pd4   = (float4*)(dstS + Epad);

  const int nchunk = (N + 255) / 256;

  hipMemsetAsync(deg, 0, (size_t)N * sizeof(int), stream);
  hipMemsetAsync(numer, 0, 2 * N64 * sizeof(float), stream);
  if (Epad > Etot) {
    hipMemsetAsync(dstS + Etot, 0xFF, (size_t)(Epad - Etot) * sizeof(int), stream);
    hipMemsetAsync(srcS + Etot, 0, (size_t)(Epad - Etot) * sizeof(int), stream);
    hipMemsetAsync(pd4 + Etot, 0, (size_t)(Epad - Etot) * sizeof(float4), stream);
  }

  hist_kernel<<<1024, 256, 0, stream>>>(ei, deg, E, Etot);
  scanA_kernel<<<nchunk, 256, 0, stream>>>(deg, chunkSum, N);
  scanB_kernel<<<1, 256, 0, stream>>>(chunkSum, chunkPre, nchunk);
  scanC_kernel<<<nchunk, 256, 0, stream>>>(deg, chunkPre, cursor, N);
  scatter_kernel<<<1024, 256, 0, stream>>>(ei, cursor, pos, srcS, dstS, pd4, E, Etot);

  const int ntileN = (N + 63) / 64;
  const int nblkN  = ntileN < 768 ? ntileN : 768;
  node_mfma_kernel<<<nblkN, 256, 0, stream>>>(x, W_in, b_in, W_lin, W_src, W_dst,
                                              a_src, a_dst, v, N);

  const int G   = Epad / 16;
  const int NB  = 768;
  const int gpw = (G + NB * 4 - 1) / (NB * 4);
  edge_kernel<<<NB, 256, 0, stream>>>(srcS, dstS, pd4, a_src, a_dst, v,
      pos_W1, pos_b1, pos_g, pos_beta, pos_W2, pos_b2,
      att_W1, att_b1, att_g, att_beta, att_W2, att_b2,
      numer, denom, G, gpw);

  out_mfma_kernel<<<nblkN, 256, 0, stream>>>(numer, denom, W_out, b_out, (float*)d_out, N);
}